// Round 10
// baseline (260.488 us; speedup 1.0000x reference)
//
#include <hip/hip_runtime.h>
#include <hip/hip_bf16.h>

#define HD __device__ __forceinline__
typedef unsigned short u16;
typedef __attribute__((ext_vector_type(8))) short bf16x8;
typedef __attribute__((ext_vector_type(4))) float f32x4;

// round-to-nearest-even fp32 -> bf16 bits
HD u16 f2b(float f){
  unsigned u = __float_as_uint(f);
  unsigned r = (u + 0x7fffu + ((u>>16)&1u)) >> 16;
  return (u16)r;
}
HD float b2f(short s){ return __uint_as_float(((unsigned)(u16)s)<<16); }

// ---------------- shared GEMM body ----------------
// Cb[M,N] = A[M,K] @ Bt[N,K]^T (bf16 out) + fused alpha epilogue (see R8).
// tile 128x128, BK=32, 256 thr = 4 waves 2x2. AF32: fp32 A, bf16-rounded
// in-register during staging (bit-identical to a separate cast pass).
template<int AF32>
HD void gemm_body(const void* Ap, const u16* __restrict__ Bt,
                  u16* __restrict__ Cb,
                  const float* __restrict__ a_s, const float* __restrict__ a_d,
                  float* __restrict__ asrc, float* __restrict__ adst,
                  int M, int N, int K, int bidx, int bidy, char* lds){
  char* As = lds;
  char* Bs = lds + 128*80;   // row stride 80B - conflict-free
  const int tid = threadIdx.x;
  const int lane = tid & 63, w = tid >> 6;
  const int wr = w >> 1, wc = w & 1;
  const int l15 = lane & 15, l4 = lane >> 4;
  const int m0 = bidy*128, n0 = bidx*128;

  f32x4 acc[4][4] = {};
  int aoff[4], boff[4];
  #pragma unroll
  for (int i=0;i<4;++i) aoff[i] = (wr*64 + i*16 + l15)*80 + l4*16;
  #pragma unroll
  for (int j=0;j<4;++j) boff[j] = (wc*64 + j*16 + l15)*80 + l4*16;

  for (int k0=0; k0<K; k0+=32){
    #pragma unroll
    for (int i=0;i<2;++i){
      int cid = tid*2+i;
      int r = cid>>2, c = cid&3;
      int row = m0 + r;
      if (AF32){
        const float* A = (const float*)Ap;
        float4 v0 = make_float4(0.f,0.f,0.f,0.f), v1 = v0;
        if (row < M){
          v0 = *(const float4*)(A + (size_t)row*K + k0 + c*8);
          v1 = *(const float4*)(A + (size_t)row*K + k0 + c*8 + 4);
        }
        ushort4 o0, o1;
        o0.x=f2b(v0.x); o0.y=f2b(v0.y); o0.z=f2b(v0.z); o0.w=f2b(v0.w);
        o1.x=f2b(v1.x); o1.y=f2b(v1.y); o1.z=f2b(v1.z); o1.w=f2b(v1.w);
        *(ushort4*)(As + r*80 + c*16)     = o0;
        *(ushort4*)(As + r*80 + c*16 + 8) = o1;
      } else {
        const u16* A = (const u16*)Ap;
        float4 v = make_float4(0.f,0.f,0.f,0.f);
        if (row < M) v = *(const float4*)(A + (size_t)row*K + k0 + c*8);
        *(float4*)(As + r*80 + c*16) = v;
      }
    }
    #pragma unroll
    for (int i=0;i<2;++i){
      int cid = tid*2+i;
      int r = cid>>2, c = cid&3;
      float4 v = *(const float4*)(Bt + (size_t)(n0+r)*K + k0 + c*8);
      *(float4*)(Bs + r*80 + c*16) = v;
    }
    __syncthreads();
    bf16x8 a[4], b[4];
    #pragma unroll
    for (int i=0;i<4;++i) a[i] = *reinterpret_cast<const bf16x8*>(As + aoff[i]);
    #pragma unroll
    for (int j=0;j<4;++j) b[j] = *reinterpret_cast<const bf16x8*>(Bs + boff[j]);
    #pragma unroll
    for (int i=0;i<4;++i)
      #pragma unroll
      for (int j=0;j<4;++j)
        acc[i][j] = __builtin_amdgcn_mfma_f32_16x16x32_bf16(a[i], b[j], acc[i][j], 0,0,0);
    __syncthreads();
  }

  const int head = (n0>>6) + wc;
  float sv[4][4] = {}, dv[4][4] = {};
  #pragma unroll
  for (int i=0;i<4;++i){
    #pragma unroll
    for (int j=0;j<4;++j){
      int col = n0 + wc*64 + j*16 + l15;
      float asv = a_s[col], adv = a_d[col];
      #pragma unroll
      for (int r=0;r<4;++r){
        int row = m0 + wr*64 + i*16 + l4*4 + r;
        u16 bits = f2b(acc[i][j][r]);
        float valf = b2f((short)bits);
        if (row < M) Cb[(size_t)row*N + col] = bits;
        sv[i][r] = fmaf(valf, asv, sv[i][r]);
        dv[i][r] = fmaf(valf, adv, dv[i][r]);
      }
    }
  }
  #pragma unroll
  for (int i=0;i<4;++i){
    #pragma unroll
    for (int r=0;r<4;++r){
      float s_ = sv[i][r], d_ = dv[i][r];
      #pragma unroll
      for (int mask=1; mask<16; mask<<=1){
        s_ += __shfl_xor(s_, mask);
        d_ += __shfl_xor(d_, mask);
      }
      if (l15==0){
        int row = m0 + wr*64 + i*16 + l4*4 + r;
        if (row < M){ asrc[row*8+head] = s_; adst[row*8+head] = d_; }
      }
    }
  }
}

// ---------------- mega kernel A: count | W1t | W2t | wedot ----------------
__global__ __launch_bounds__(256) void k_prepA(
    const int* __restrict__ dst, const float* __restrict__ ea,
    int* cnt, float* easum, int E, int nbCount,
    const float* __restrict__ W1, u16* __restrict__ W1t,
    const float* __restrict__ W2, u16* __restrict__ W2t,
    const float* __restrict__ We1, const float* __restrict__ ae1,
    const float* __restrict__ We2, const float* __restrict__ ae2,
    float* wedot){
  __shared__ float T[64][65];
  int bx = blockIdx.x;
  int tid = threadIdx.x;
  if (bx < nbCount){
    int e = bx*256 + tid;
    if (e<E){
      int d = dst[e];
      atomicAdd(&cnt[d],1);
      atomicAdd(&easum[d], ea[e]);
    }
    return;
  }
  bx -= nbCount;
  if (bx < 16 + 64){
    const float* W; u16* Wt; int K, t;
    if (bx < 16){ t = bx;      W = W1; Wt = W1t; K = 128; }
    else        { t = bx - 16; W = W2; Wt = W2t; K = 512; }
    const int Nn = 512, nt = 8;
    int k0 = (t/nt)*64, n0 = (t%nt)*64;
    #pragma unroll
    for (int i=0;i<16;++i){
      int id = i*256 + tid;
      int r = id>>6, c = id&63;
      T[r][c] = W[(size_t)(k0+r)*Nn + n0 + c];
    }
    __syncthreads();
    #pragma unroll
    for (int i=0;i<16;++i){
      int id = i*256 + tid;
      int rr = id>>6, cc = id&63;
      Wt[(size_t)(n0+rr)*K + k0 + cc] = f2b(T[cc][rr]);
    }
    return;
  }
  int idx = bx - 80;
  int which = idx>>1, hg = idx&1;
  const float* We = which? We2 : We1;
  const float* ae = which? ae2 : ae1;
  int wv = tid>>6, lane = tid&63;
  int head = hg*4 + wv;
  float p = We[head*64+lane]*ae[head*64+lane];
  #pragma unroll
  for (int o=32;o;o>>=1) p += __shfl_down(p,o);
  if (lane==0) wedot[which*8+head] = p;
}

// ---------------- kernel B: scan | loop-attr ----------------
__global__ __launch_bounds__(256) void k_scanla(
    const int* __restrict__ cnt, int* offs, int N,
    const float* __restrict__ easum, float* la){
  __shared__ int slds[256];
  int bx = blockIdx.x;
  int tid = threadIdx.x;
  if (bx == 0){
    const int chunk = (N + 255)/256;
    const int b = tid*chunk;
    int s = 0;
    for (int i=0;i<chunk;++i){ int idx=b+i; if (idx<N) s += cnt[idx]; }
    slds[tid] = s;
    __syncthreads();
    #pragma unroll
    for (int off=1; off<256; off<<=1){
      int t = (tid>=off)? slds[tid-off] : 0;
      __syncthreads();
      slds[tid] += t;
      __syncthreads();
    }
    int excl = slds[tid] - s;
    for (int i=0;i<chunk;++i){
      int idx=b+i;
      if (idx<N){ offs[idx] = excl; excl += cnt[idx]; }
    }
    if (tid==255) offs[N] = slds[255];
    return;
  }
  int n = (bx-1)*256 + tid;
  if (n<N) la[n] = easum[n] / fmaxf((float)cnt[n], 1.f);
}

// ---------------- kernel C: scatter || GEMM1 (fp32 A) ----------------
__global__ __launch_bounds__(256) void k_scatgemm(
    const int* __restrict__ src, const int* __restrict__ dst,
    const float* __restrict__ ea, const int* __restrict__ offs,
    int* fill, int* srcs, float* eas, int E, int nbScat,
    const float* __restrict__ x, const u16* __restrict__ W1t,
    u16* __restrict__ hb1,
    const float* __restrict__ a_s, const float* __restrict__ a_d,
    float* __restrict__ asrc, float* __restrict__ adst,
    int M, int Nd, int K){
  __shared__ char glds[256*80];
  int bx = blockIdx.x;
  if (bx < nbScat){
    int e = bx*256 + threadIdx.x;
    if (e<E){
      int d = dst[e];
      int p = offs[d] + atomicAdd(&fill[d],1);
      srcs[p] = src[e];
      eas[p]  = ea[e];
    }
    return;
  }
  int t = bx - nbScat;
  gemm_body<1>(x, W1t, hb1, a_s, a_d, asrc, adst, M, Nd, K, t%4, t/4, glds);
}

// standalone GEMM (bf16 A) for layer 2
__global__ __launch_bounds__(256) void k_gemm_mfma(
    const u16* __restrict__ A, const u16* __restrict__ Bt,
    u16* __restrict__ Cb,
    const float* __restrict__ a_s, const float* __restrict__ a_d,
    float* __restrict__ asrc, float* __restrict__ adst,
    int M, int N, int K){
  __shared__ char lds[256*80];
  gemm_body<0>(A, Bt, Cb, a_s, a_d, asrc, adst, M, N, K,
               blockIdx.x, blockIdx.y, lds);
}

// ---------- channel-sliced, XCD-pinned online-softmax aggregate ----------
// 4 slices x 128 channels (= 2 heads). slice = (blockIdx%8)>>1 so each XCD
// pair touches only its 2.5 MB hb slice -> L2-resident. Per block: 4 waves =
// 4 nodes, same slice. Producer lanes (edge=lane>>1, head=slice*2+(lane&1))
// compute alpha for 32 edges/round; consumer lanes hold 2 channels
// (c0 = slice*128 + lane*2, head myh = slice*2 + (lane>>5)); register-only
// alpha exchange; online max-rescale. No scratch, no fence.
__global__ __launch_bounds__(256) void k_flashagg(const u16* __restrict__ hb,
    const int* __restrict__ srcs, const float* __restrict__ eas,
    const int* __restrict__ offs,
    const float* __restrict__ asrc, const float* __restrict__ adst,
    const float* __restrict__ wedot, const float* __restrict__ la,
    const float* __restrict__ bias,
    u16* __restrict__ outb,
    int N, int G, int relu_flag, int self_flag){
  int b = blockIdx.x;
  int slice = (b & 7) >> 1, sub = b & 1;
  int g = (b >> 3)*2 + sub;
  if (g >= G) return;
  int n = g*4 + (int)(threadIdx.x >> 6);
  if (n >= N) return;
  int lane = threadIdx.x & 63;
  int hp = slice*2 + (lane & 1);     // producer head
  int myh = slice*2 + (lane >> 5);   // consumer head
  int hb_ = lane >> 5;
  int c0 = slice*128 + lane*2;       // consumer channel pair
  int beg = offs[n], end = offs[n+1];
  float wd_p = wedot[hp];
  float adn_p = adst[n*8+hp];

  float aselfa = -1e30f;
  if (self_flag){
    float a = asrc[n*8+myh] + adst[n*8+myh] + la[n]*wedot[myh];
    aselfa = a>0.f ? a : 0.2f*a;
  }
  float m = self_flag ? aselfa : -1e30f;
  float s = 0.f;
  float acc0 = 0.f, acc1 = 0.f;

  for (int p0=beg; p0<end; p0+=32){
    // producer: alpha for edge p0+(lane>>1), head hp
    int p = p0 + (lane>>1);
    float a = -1e30f; int sp = 0;
    if (p < end){
      sp = srcs[p];
      float a0 = asrc[sp*8+hp] + adn_p + eas[p]*wd_p;
      a = a0>0.f ? a0 : 0.2f*a0;
    }
    // consumer: 32 alphas (own head) + 32 src indices, register exchange
    float av[32]; int se[32];
    #pragma unroll
    for (int e=0;e<32;++e){ av[e] = __shfl(a, e*2 + hb_); se[e] = __shfl(sp, e*2); }
    float mo = m;
    #pragma unroll
    for (int e=0;e<32;++e) mo = fmaxf(mo, av[e]);
    float f = __expf(m - mo);
    m = mo;
    s *= f; acc0 *= f; acc1 *= f;
    #pragma unroll
    for (int e=0;e<32;++e){
      if (p0 + e < end){                 // wave-uniform -> scalar skip
        float ee = __expf(av[e] - m);
        s += ee;
        unsigned two = *(const unsigned*)(hb + (size_t)se[e]*512 + c0);
        acc0 = fmaf(ee, b2f((short)(two & 0xffff)), acc0);
        acc1 = fmaf(ee, b2f((short)(two >> 16)), acc1);
      }
    }
  }
  if (self_flag){
    float xs = __expf(aselfa - m);       // aselfa <= m by init
    s += xs;
    unsigned two = *(const unsigned*)(hb + (size_t)n*512 + c0);
    acc0 = fmaf(xs, b2f((short)(two & 0xffff)), acc0);
    acc1 = fmaf(xs, b2f((short)(two >> 16)), acc1);
  }
  float iv = 1.f/(s + 1e-16f);
  float2 bv = *(const float2*)(bias + c0);
  float v0 = acc0*iv + bv.x;
  float v1 = acc1*iv + bv.y;
  if (relu_flag){ v0 = fmaxf(v0,0.f); v1 = fmaxf(v1,0.f); }
  unsigned ou = ((unsigned)f2b(v1)<<16) | f2b(v0);
  *(unsigned*)(outb + (size_t)n*512 + c0) = ou;
}

// column mean over bf16 rows: 512 threads (one per channel), 16 rows/block
__global__ __launch_bounds__(512) void k_colmean(const u16* __restrict__ out2b,
                          float* __restrict__ o, int N, float invN){
  int c = threadIdx.x;
  int n0 = blockIdx.x*16;
  int nend = min(n0+16, N);
  float s = 0.f;
  for (int n=n0;n<nend;++n) s += b2f(out2b[(size_t)n*512 + c]);
  atomicAdd(&o[c], s*invN);
}

extern "C" void kernel_launch(void* const* d_in, const int* in_sizes, int n_in,
                              void* d_out, int out_size, void* d_ws, size_t ws_size,
                              hipStream_t stream){
  const float* x   = (const float*)d_in[0];
  const int* eidx  = (const int*)d_in[1];
  const float* ea  = (const float*)d_in[2];
  const float* W1  = (const float*)d_in[3];
  const float* We1 = (const float*)d_in[4];
  const float* as1 = (const float*)d_in[5];
  const float* ad1 = (const float*)d_in[6];
  const float* ae1 = (const float*)d_in[7];
  const float* b1  = (const float*)d_in[8];
  const float* W2  = (const float*)d_in[9];
  const float* We2 = (const float*)d_in[10];
  const float* as2 = (const float*)d_in[11];
  const float* ad2 = (const float*)d_in[12];
  const float* ae2 = (const float*)d_in[13];
  const float* b2  = (const float*)d_in[14];
  float* outp = (float*)d_out;

  const int FIN = 128, D1 = 512;
  const int N = in_sizes[0]/FIN;
  const int E = in_sizes[1]/2;
  const int* srcA = eidx;
  const int* dstA = eidx + E;

  char* ws = (char*)d_ws;
  size_t o = 0;
  auto alloc = [&](size_t bytes)->void*{
    void* p = ws + o; o = (o + bytes + 255) & ~(size_t)255; return p;
  };
  u16*   hb1   = (u16*)  alloc((size_t)N*D1*2);   // layer1 features, bf16
  u16*   hb2   = (u16*)  alloc((size_t)N*D1*2);   // layer2 features, bf16
  u16*   out1rb= (u16*)  alloc((size_t)N*D1*2);   // relu(layer1 out), bf16
  u16*   out2b = (u16*)  alloc((size_t)N*D1*2);   // layer2 out, bf16
  u16*   W1t   = (u16*)  alloc((size_t)D1*FIN*2); // [512][128]
  u16*   W2t   = (u16*)  alloc((size_t)D1*D1*2);  // [512][512]
  int*   srcs  = (int*)  alloc((size_t)E*4);
  float* eas   = (float*)alloc((size_t)E*4);
  int*   offs  = (int*)  alloc((size_t)(N+1)*4);
  size_t zbeg = o;
  int*   cnt   = (int*)  alloc((size_t)N*4);
  int*   fill  = (int*)  alloc((size_t)N*4);
  float* easum = (float*)alloc((size_t)N*4);
  size_t zend = o;
  float* asrc  = (float*)alloc((size_t)N*8*4);
  float* adst  = (float*)alloc((size_t)N*8*4);
  float* la    = (float*)alloc((size_t)N*4);
  float* wedot = (float*)alloc(64);
  (void)ws_size; (void)n_in;

  hipMemsetAsync(ws + zbeg, 0, zend - zbeg, stream);
  hipMemsetAsync(d_out, 0, (size_t)out_size*sizeof(float), stream);

  dim3 b256(256);
  int ge = (E+255)/256;          // 625
  int G  = (N+3)/4;              // node groups of 4
  int nbFA = 8*((G+1)/2);        // slice-pinned grid (4 slices x G, %8 aligned)

  // A: count | W1 transpose | W2 transpose | wedot
  k_prepA<<<ge + 16 + 64 + 4, b256, 0, stream>>>(
      dstA, ea, cnt, easum, E, ge,
      W1, W1t, W2, W2t, We1, ae1, We2, ae2, wedot);

  // B: scan | loop-attr
  k_scanla<<<1 + (N+255)/256, b256, 0, stream>>>(cnt, offs, N, easum, la);

  // C: scatter || GEMM1 (fp32 A, in-register bf16 round)
  int nbG1 = (D1/128)*((N+127)/128);
  k_scatgemm<<<ge + nbG1, b256, 0, stream>>>(
      srcA, dstA, ea, offs, fill, srcs, eas, E, ge,
      x, W1t, hb1, as1, ad1, asrc, adst, N, D1, FIN);

  // D: layer-1 flash aggregate (sliced)
  k_flashagg<<<nbFA, b256, 0, stream>>>(hb1, srcs, eas, offs, asrc, adst,
                                        wedot, la, b1, out1rb, N, G, 1, 0);

  // E: GEMM2 (bf16 A) + alpha epilogue
  k_gemm_mfma<<<dim3(D1/128, (N+127)/128), b256, 0, stream>>>(
      out1rb, W2t, hb2, as2, ad2, asrc, adst, N, D1, D1);

  // F: layer-2 flash aggregate (self loops, fill='mean')
  k_flashagg<<<nbFA, b256, 0, stream>>>(hb2, srcs, eas, offs, asrc, adst,
                                        wedot+8, la, b2, out2b, N, G, 0, 1);

  // G: mean over nodes
  k_colmean<<<(N+15)/16, 512, 0, stream>>>(out2b, outp, N, 1.0f/(float)N);
}

// Round 11
// 189.348 us; speedup vs baseline: 1.3757x; 1.3757x over previous
//
#include <hip/hip_runtime.h>
#include <hip/hip_bf16.h>

#define HD __device__ __forceinline__
typedef unsigned short u16;
typedef __attribute__((ext_vector_type(8))) short bf16x8;
typedef __attribute__((ext_vector_type(4))) float f32x4;

// round-to-nearest-even fp32 -> bf16 bits
HD u16 f2b(float f){
  unsigned u = __float_as_uint(f);
  unsigned r = (u + 0x7fffu + ((u>>16)&1u)) >> 16;
  return (u16)r;
}
HD float b2f(short s){ return __uint_as_float(((unsigned)(u16)s)<<16); }

// ---------------- shared GEMM body ----------------
// Cb[M,N] = A[M,K] @ Bt[N,K]^T (bf16 out) + fused alpha epilogue (see R8).
// tile 128x128, BK=32, 256 thr = 4 waves 2x2. AF32: fp32 A, bf16-rounded
// in-register during staging (bit-identical to a separate cast pass).
template<int AF32>
HD void gemm_body(const void* Ap, const u16* __restrict__ Bt,
                  u16* __restrict__ Cb,
                  const float* __restrict__ a_s, const float* __restrict__ a_d,
                  float* __restrict__ asrc, float* __restrict__ adst,
                  int M, int N, int K, int bidx, int bidy, char* lds){
  char* As = lds;
  char* Bs = lds + 128*80;   // row stride 80B - conflict-free
  const int tid = threadIdx.x;
  const int lane = tid & 63, w = tid >> 6;
  const int wr = w >> 1, wc = w & 1;
  const int l15 = lane & 15, l4 = lane >> 4;
  const int m0 = bidy*128, n0 = bidx*128;

  f32x4 acc[4][4] = {};
  int aoff[4], boff[4];
  #pragma unroll
  for (int i=0;i<4;++i) aoff[i] = (wr*64 + i*16 + l15)*80 + l4*16;
  #pragma unroll
  for (int j=0;j<4;++j) boff[j] = (wc*64 + j*16 + l15)*80 + l4*16;

  for (int k0=0; k0<K; k0+=32){
    #pragma unroll
    for (int i=0;i<2;++i){
      int cid = tid*2+i;
      int r = cid>>2, c = cid&3;
      int row = m0 + r;
      if (AF32){
        const float* A = (const float*)Ap;
        float4 v0 = make_float4(0.f,0.f,0.f,0.f), v1 = v0;
        if (row < M){
          v0 = *(const float4*)(A + (size_t)row*K + k0 + c*8);
          v1 = *(const float4*)(A + (size_t)row*K + k0 + c*8 + 4);
        }
        ushort4 o0, o1;
        o0.x=f2b(v0.x); o0.y=f2b(v0.y); o0.z=f2b(v0.z); o0.w=f2b(v0.w);
        o1.x=f2b(v1.x); o1.y=f2b(v1.y); o1.z=f2b(v1.z); o1.w=f2b(v1.w);
        *(ushort4*)(As + r*80 + c*16)     = o0;
        *(ushort4*)(As + r*80 + c*16 + 8) = o1;
      } else {
        const u16* A = (const u16*)Ap;
        float4 v = make_float4(0.f,0.f,0.f,0.f);
        if (row < M) v = *(const float4*)(A + (size_t)row*K + k0 + c*8);
        *(float4*)(As + r*80 + c*16) = v;
      }
    }
    #pragma unroll
    for (int i=0;i<2;++i){
      int cid = tid*2+i;
      int r = cid>>2, c = cid&3;
      float4 v = *(const float4*)(Bt + (size_t)(n0+r)*K + k0 + c*8);
      *(float4*)(Bs + r*80 + c*16) = v;
    }
    __syncthreads();
    bf16x8 a[4], b[4];
    #pragma unroll
    for (int i=0;i<4;++i) a[i] = *reinterpret_cast<const bf16x8*>(As + aoff[i]);
    #pragma unroll
    for (int j=0;j<4;++j) b[j] = *reinterpret_cast<const bf16x8*>(Bs + boff[j]);
    #pragma unroll
    for (int i=0;i<4;++i)
      #pragma unroll
      for (int j=0;j<4;++j)
        acc[i][j] = __builtin_amdgcn_mfma_f32_16x16x32_bf16(a[i], b[j], acc[i][j], 0,0,0);
    __syncthreads();
  }

  const int head = (n0>>6) + wc;
  float sv[4][4] = {}, dv[4][4] = {};
  #pragma unroll
  for (int i=0;i<4;++i){
    #pragma unroll
    for (int j=0;j<4;++j){
      int col = n0 + wc*64 + j*16 + l15;
      float asv = a_s[col], adv = a_d[col];
      #pragma unroll
      for (int r=0;r<4;++r){
        int row = m0 + wr*64 + i*16 + l4*4 + r;
        u16 bits = f2b(acc[i][j][r]);
        float valf = b2f((short)bits);
        if (row < M) Cb[(size_t)row*N + col] = bits;
        sv[i][r] = fmaf(valf, asv, sv[i][r]);
        dv[i][r] = fmaf(valf, adv, dv[i][r]);
      }
    }
  }
  #pragma unroll
  for (int i=0;i<4;++i){
    #pragma unroll
    for (int r=0;r<4;++r){
      float s_ = sv[i][r], d_ = dv[i][r];
      #pragma unroll
      for (int mask=1; mask<16; mask<<=1){
        s_ += __shfl_xor(s_, mask);
        d_ += __shfl_xor(d_, mask);
      }
      if (l15==0){
        int row = m0 + wr*64 + i*16 + l4*4 + r;
        if (row < M){ asrc[row*8+head] = s_; adst[row*8+head] = d_; }
      }
    }
  }
}

// ---------------- mega kernel A: count | W1t | W2t | wedot ----------------
__global__ __launch_bounds__(256) void k_prepA(
    const int* __restrict__ dst, const float* __restrict__ ea,
    int* cnt, float* easum, int E, int nbCount,
    const float* __restrict__ W1, u16* __restrict__ W1t,
    const float* __restrict__ W2, u16* __restrict__ W2t,
    const float* __restrict__ We1, const float* __restrict__ ae1,
    const float* __restrict__ We2, const float* __restrict__ ae2,
    float* wedot){
  __shared__ float T[64][65];
  int bx = blockIdx.x;
  int tid = threadIdx.x;
  if (bx < nbCount){
    int e = bx*256 + tid;
    if (e<E){
      int d = dst[e];
      atomicAdd(&cnt[d],1);
      atomicAdd(&easum[d], ea[e]);
    }
    return;
  }
  bx -= nbCount;
  if (bx < 16 + 64){
    const float* W; u16* Wt; int K, t;
    if (bx < 16){ t = bx;      W = W1; Wt = W1t; K = 128; }
    else        { t = bx - 16; W = W2; Wt = W2t; K = 512; }
    const int Nn = 512, nt = 8;
    int k0 = (t/nt)*64, n0 = (t%nt)*64;
    #pragma unroll
    for (int i=0;i<16;++i){
      int id = i*256 + tid;
      int r = id>>6, c = id&63;
      T[r][c] = W[(size_t)(k0+r)*Nn + n0 + c];
    }
    __syncthreads();
    #pragma unroll
    for (int i=0;i<16;++i){
      int id = i*256 + tid;
      int rr = id>>6, cc = id&63;
      Wt[(size_t)(n0+rr)*K + k0 + cc] = f2b(T[cc][rr]);
    }
    return;
  }
  int idx = bx - 80;
  int which = idx>>1, hg = idx&1;
  const float* We = which? We2 : We1;
  const float* ae = which? ae2 : ae1;
  int wv = tid>>6, lane = tid&63;
  int head = hg*4 + wv;
  float p = We[head*64+lane]*ae[head*64+lane];
  #pragma unroll
  for (int o=32;o;o>>=1) p += __shfl_down(p,o);
  if (lane==0) wedot[which*8+head] = p;
}

// ---------------- kernel B: scan | loop-attr ----------------
__global__ __launch_bounds__(256) void k_scanla(
    const int* __restrict__ cnt, int* offs, int N,
    const float* __restrict__ easum, float* la){
  __shared__ int slds[256];
  int bx = blockIdx.x;
  int tid = threadIdx.x;
  if (bx == 0){
    const int chunk = (N + 255)/256;
    const int b = tid*chunk;
    int s = 0;
    for (int i=0;i<chunk;++i){ int idx=b+i; if (idx<N) s += cnt[idx]; }
    slds[tid] = s;
    __syncthreads();
    #pragma unroll
    for (int off=1; off<256; off<<=1){
      int t = (tid>=off)? slds[tid-off] : 0;
      __syncthreads();
      slds[tid] += t;
      __syncthreads();
    }
    int excl = slds[tid] - s;
    for (int i=0;i<chunk;++i){
      int idx=b+i;
      if (idx<N){ offs[idx] = excl; excl += cnt[idx]; }
    }
    if (tid==255) offs[N] = slds[255];
    return;
  }
  int n = (bx-1)*256 + tid;
  if (n<N) la[n] = easum[n] / fmaxf((float)cnt[n], 1.f);
}

// ---------------- kernel C: scatter || GEMM1 (fp32 A) ----------------
__global__ __launch_bounds__(256) void k_scatgemm(
    const int* __restrict__ src, const int* __restrict__ dst,
    const float* __restrict__ ea, const int* __restrict__ offs,
    int* fill, int* srcs, float* eas, int E, int nbScat,
    const float* __restrict__ x, const u16* __restrict__ W1t,
    u16* __restrict__ hb1,
    const float* __restrict__ a_s, const float* __restrict__ a_d,
    float* __restrict__ asrc, float* __restrict__ adst,
    int M, int Nd, int K){
  __shared__ char glds[256*80];
  int bx = blockIdx.x;
  if (bx < nbScat){
    int e = bx*256 + threadIdx.x;
    if (e<E){
      int d = dst[e];
      int p = offs[d] + atomicAdd(&fill[d],1);
      srcs[p] = src[e];
      eas[p]  = ea[e];
    }
    return;
  }
  int t = bx - nbScat;
  gemm_body<1>(x, W1t, hb1, a_s, a_d, asrc, adst, M, Nd, K, t%4, t/4, glds);
}

// standalone GEMM (bf16 A) for layer 2
__global__ __launch_bounds__(256) void k_gemm_mfma(
    const u16* __restrict__ A, const u16* __restrict__ Bt,
    u16* __restrict__ Cb,
    const float* __restrict__ a_s, const float* __restrict__ a_d,
    float* __restrict__ asrc, float* __restrict__ adst,
    int M, int N, int K){
  __shared__ char lds[256*80];
  gemm_body<0>(A, Bt, Cb, a_s, a_d, asrc, adst, M, N, K,
               blockIdx.x, blockIdx.y, lds);
}

// -------- online-softmax aggregate: 2 waves/node, unified head-space --------
// Wave wv of node n handles heads wv*4..wv*4+4 (channels wv*256..+256).
// Lane role (BOTH producer & consumer): head hh = wv*4 + (lane>>4),
// edge slot esub = lane&15, channels c0 = hh*64 + esub*4 (8B).
// Per 16-edge round: each lane computes ONE alpha (its head, its edge slot),
// per-head max/sum via width-16 shfl_xor reduces, exp on PRODUCER side
// (1 exp/lane/round instead of 16), exchange exponentiated weights + src
// indices via width-16 shfl. Online max-rescale; no scratch, no fence.
__global__ __launch_bounds__(256) void k_flashagg(const u16* __restrict__ hb,
    const int* __restrict__ srcs, const float* __restrict__ eas,
    const int* __restrict__ offs,
    const float* __restrict__ asrc, const float* __restrict__ adst,
    const float* __restrict__ wedot, const float* __restrict__ la,
    const float* __restrict__ bias,
    u16* __restrict__ outb,
    int N, int relu_flag, int self_flag){
  int n = blockIdx.x*2 + (int)(threadIdx.x>>7);
  if (n>=N) return;
  int wv = (threadIdx.x>>6)&1;
  int lane = threadIdx.x&63;
  int hh = wv*4 + (lane>>4);       // head (producer AND consumer)
  int esub = lane&15;              // edge slot
  int c0 = hh*64 + esub*4;         // 4 channels (8B)
  int beg = offs[n], end = offs[n+1];
  float wd = wedot[hh];
  float adn = adst[n*8+hh];

  float aselfa = -1e30f;
  if (self_flag){
    float a = asrc[n*8+hh] + adn + la[n]*wd;
    aselfa = a>0.f ? a : 0.2f*a;
  }
  float m = self_flag ? aselfa : -1e30f;
  float s = 0.f;
  float acc0=0.f, acc1=0.f, acc2=0.f, acc3=0.f;

  for (int p0=beg; p0<end; p0+=16){
    int p = p0 + esub;
    float a = -1e30f; int sp = 0;
    if (p < end){
      sp = srcs[p];
      float a0 = asrc[sp*8+hh] + adn + eas[p]*wd;
      a = a0>0.f ? a0 : 0.2f*a0;
    }
    // per-head max over the 16 edge slots
    float g = a;
    g = fmaxf(g, __shfl_xor(g, 1, 16));
    g = fmaxf(g, __shfl_xor(g, 2, 16));
    g = fmaxf(g, __shfl_xor(g, 4, 16));
    g = fmaxf(g, __shfl_xor(g, 8, 16));
    float mo = fmaxf(m, g);
    float f = __expf(m - mo);      // first round: exp(-inf)=0, acc already 0
    m = mo;
    float ee = __expf(a - m);      // invalid slots: exp(-inf)=0
    // per-head sum of this round's weights
    float sr = ee;
    sr += __shfl_xor(sr, 1, 16);
    sr += __shfl_xor(sr, 2, 16);
    sr += __shfl_xor(sr, 4, 16);
    sr += __shfl_xor(sr, 8, 16);
    s = s*f + sr;
    acc0*=f; acc1*=f; acc2*=f; acc3*=f;
    // consume: gather 4 channels per edge, weight by exchanged ee
    #pragma unroll
    for (int e=0;e<16;++e){
      if (p0 + e < end){                 // wave-uniform -> cheap skip
        float w_ = __shfl(ee, e, 16);
        int   se = __shfl(sp, e, 16);
        uint2 two = *(const uint2*)(hb + (size_t)se*512 + c0);
        acc0 = fmaf(w_, b2f((short)(two.x & 0xffff)), acc0);
        acc1 = fmaf(w_, b2f((short)(two.x >> 16)),    acc1);
        acc2 = fmaf(w_, b2f((short)(two.y & 0xffff)), acc2);
        acc3 = fmaf(w_, b2f((short)(two.y >> 16)),    acc3);
      }
    }
  }
  if (self_flag){
    float xs = __expf(aselfa - m);       // aselfa <= m by init
    s += xs;
    uint2 two = *(const uint2*)(hb + (size_t)n*512 + c0);
    acc0 = fmaf(xs, b2f((short)(two.x & 0xffff)), acc0);
    acc1 = fmaf(xs, b2f((short)(two.x >> 16)),    acc1);
    acc2 = fmaf(xs, b2f((short)(two.y & 0xffff)), acc2);
    acc3 = fmaf(xs, b2f((short)(two.y >> 16)),    acc3);
  }
  float iv = 1.f/(s + 1e-16f);
  float4 bv = *(const float4*)(bias + c0);
  float v0 = acc0*iv + bv.x;
  float v1 = acc1*iv + bv.y;
  float v2 = acc2*iv + bv.z;
  float v3 = acc3*iv + bv.w;
  if (relu_flag){
    v0=fmaxf(v0,0.f); v1=fmaxf(v1,0.f); v2=fmaxf(v2,0.f); v3=fmaxf(v3,0.f);
  }
  uint2 ou;
  ou.x = ((unsigned)f2b(v1)<<16) | f2b(v0);
  ou.y = ((unsigned)f2b(v3)<<16) | f2b(v2);
  *(uint2*)(outb + (size_t)n*512 + c0) = ou;
}

// column mean over bf16 rows: 512 threads (one per channel), 16 rows/block
__global__ __launch_bounds__(512) void k_colmean(const u16* __restrict__ out2b,
                          float* __restrict__ o, int N, float invN){
  int c = threadIdx.x;
  int n0 = blockIdx.x*16;
  int nend = min(n0+16, N);
  float s = 0.f;
  for (int n=n0;n<nend;++n) s += b2f(out2b[(size_t)n*512 + c]);
  atomicAdd(&o[c], s*invN);
}

extern "C" void kernel_launch(void* const* d_in, const int* in_sizes, int n_in,
                              void* d_out, int out_size, void* d_ws, size_t ws_size,
                              hipStream_t stream){
  const float* x   = (const float*)d_in[0];
  const int* eidx  = (const int*)d_in[1];
  const float* ea  = (const float*)d_in[2];
  const float* W1  = (const float*)d_in[3];
  const float* We1 = (const float*)d_in[4];
  const float* as1 = (const float*)d_in[5];
  const float* ad1 = (const float*)d_in[6];
  const float* ae1 = (const float*)d_in[7];
  const float* b1  = (const float*)d_in[8];
  const float* W2  = (const float*)d_in[9];
  const float* We2 = (const float*)d_in[10];
  const float* as2 = (const float*)d_in[11];
  const float* ad2 = (const float*)d_in[12];
  const float* ae2 = (const float*)d_in[13];
  const float* b2  = (const float*)d_in[14];
  float* outp = (float*)d_out;

  const int FIN = 128, D1 = 512;
  const int N = in_sizes[0]/FIN;
  const int E = in_sizes[1]/2;
  const int* srcA = eidx;
  const int* dstA = eidx + E;

  char* ws = (char*)d_ws;
  size_t o = 0;
  auto alloc = [&](size_t bytes)->void*{
    void* p = ws + o; o = (o + bytes + 255) & ~(size_t)255; return p;
  };
  u16*   hb1   = (u16*)  alloc((size_t)N*D1*2);   // layer1 features, bf16
  u16*   hb2   = (u16*)  alloc((size_t)N*D1*2);   // layer2 features, bf16
  u16*   out1rb= (u16*)  alloc((size_t)N*D1*2);   // relu(layer1 out), bf16
  u16*   out2b = (u16*)  alloc((size_t)N*D1*2);   // layer2 out, bf16
  u16*   W1t   = (u16*)  alloc((size_t)D1*FIN*2); // [512][128]
  u16*   W2t   = (u16*)  alloc((size_t)D1*D1*2);  // [512][512]
  int*   srcs  = (int*)  alloc((size_t)E*4);
  float* eas   = (float*)alloc((size_t)E*4);
  int*   offs  = (int*)  alloc((size_t)(N+1)*4);
  size_t zbeg = o;
  int*   cnt   = (int*)  alloc((size_t)N*4);
  int*   fill  = (int*)  alloc((size_t)N*4);
  float* easum = (float*)alloc((size_t)N*4);
  size_t zend = o;
  float* asrc  = (float*)alloc((size_t)N*8*4);
  float* adst  = (float*)alloc((size_t)N*8*4);
  float* la    = (float*)alloc((size_t)N*4);
  float* wedot = (float*)alloc(64);
  (void)ws_size; (void)n_in;

  hipMemsetAsync(ws + zbeg, 0, zend - zbeg, stream);
  hipMemsetAsync(d_out, 0, (size_t)out_size*sizeof(float), stream);

  dim3 b256(256);
  int ge = (E+255)/256;          // 625
  int gn2 = (N+1)/2;             // flashagg: 2 nodes/block (2 waves each)

  // A: count | W1 transpose | W2 transpose | wedot
  k_prepA<<<ge + 16 + 64 + 4, b256, 0, stream>>>(
      dstA, ea, cnt, easum, E, ge,
      W1, W1t, W2, W2t, We1, ae1, We2, ae2, wedot);

  // B: scan | loop-attr
  k_scanla<<<1 + (N+255)/256, b256, 0, stream>>>(cnt, offs, N, easum, la);

  // C: scatter || GEMM1 (fp32 A, in-register bf16 round)
  int nbG1 = (D1/128)*((N+127)/128);
  k_scatgemm<<<ge + nbG1, b256, 0, stream>>>(
      srcA, dstA, ea, offs, fill, srcs, eas, E, ge,
      x, W1t, hb1, as1, ad1, asrc, adst, N, D1, FIN);

  // D: layer-1 flash aggregate
  k_flashagg<<<gn2, b256, 0, stream>>>(hb1, srcs, eas, offs, asrc, adst,
                                       wedot, la, b1, out1rb, N, 1, 0);

  // E: GEMM2 (bf16 A) + alpha epilogue
  k_gemm_mfma<<<dim3(D1/128, (N+127)/128), b256, 0, stream>>>(
      out1rb, W2t, hb2, as2, ad2, asrc, adst, N, D1, D1);

  // F: layer-2 flash aggregate (self loops, fill='mean')
  k_flashagg<<<gn2, b256, 0, stream>>>(hb2, srcs, eas, offs, asrc, adst,
                                       wedot+8, la, b2, out2b, N, 0, 1);

  // G: mean over nodes
  k_colmean<<<(N+15)/16, 512, 0, stream>>>(out2b, outp, N, 1.0f/(float)N);
}

// Round 12
// 183.807 us; speedup vs baseline: 1.4172x; 1.0301x over previous
//
#include <hip/hip_runtime.h>
#include <hip/hip_bf16.h>

#define HD __device__ __forceinline__
typedef unsigned short u16;
typedef __attribute__((ext_vector_type(8))) short bf16x8;
typedef __attribute__((ext_vector_type(4))) float f32x4;

// round-to-nearest-even fp32 -> bf16 bits
HD u16 f2b(float f){
  unsigned u = __float_as_uint(f);
  unsigned r = (u + 0x7fffu + ((u>>16)&1u)) >> 16;
  return (u16)r;
}
HD float b2f(short s){ return __uint_as_float(((unsigned)(u16)s)<<16); }

// ---------------- shared GEMM body ----------------
// Cb[M,N] = A[M,K] @ Bt[N,K]^T (bf16 out) + fused alpha epilogue (see R8).
// tile 128x128, BK=32, 256 thr = 4 waves 2x2. AF32: fp32 A, bf16-rounded
// in-register during staging (bit-identical to a separate cast pass).
template<int AF32>
HD void gemm_body(const void* Ap, const u16* __restrict__ Bt,
                  u16* __restrict__ Cb,
                  const float* __restrict__ a_s, const float* __restrict__ a_d,
                  float* __restrict__ asrc, float* __restrict__ adst,
                  int M, int N, int K, int bidx, int bidy, char* lds){
  char* As = lds;
  char* Bs = lds + 128*80;   // row stride 80B - conflict-free
  const int tid = threadIdx.x;
  const int lane = tid & 63, w = tid >> 6;
  const int wr = w >> 1, wc = w & 1;
  const int l15 = lane & 15, l4 = lane >> 4;
  const int m0 = bidy*128, n0 = bidx*128;

  f32x4 acc[4][4] = {};
  int aoff[4], boff[4];
  #pragma unroll
  for (int i=0;i<4;++i) aoff[i] = (wr*64 + i*16 + l15)*80 + l4*16;
  #pragma unroll
  for (int j=0;j<4;++j) boff[j] = (wc*64 + j*16 + l15)*80 + l4*16;

  for (int k0=0; k0<K; k0+=32){
    #pragma unroll
    for (int i=0;i<2;++i){
      int cid = tid*2+i;
      int r = cid>>2, c = cid&3;
      int row = m0 + r;
      if (AF32){
        const float* A = (const float*)Ap;
        float4 v0 = make_float4(0.f,0.f,0.f,0.f), v1 = v0;
        if (row < M){
          v0 = *(const float4*)(A + (size_t)row*K + k0 + c*8);
          v1 = *(const float4*)(A + (size_t)row*K + k0 + c*8 + 4);
        }
        ushort4 o0, o1;
        o0.x=f2b(v0.x); o0.y=f2b(v0.y); o0.z=f2b(v0.z); o0.w=f2b(v0.w);
        o1.x=f2b(v1.x); o1.y=f2b(v1.y); o1.z=f2b(v1.z); o1.w=f2b(v1.w);
        *(ushort4*)(As + r*80 + c*16)     = o0;
        *(ushort4*)(As + r*80 + c*16 + 8) = o1;
      } else {
        const u16* A = (const u16*)Ap;
        float4 v = make_float4(0.f,0.f,0.f,0.f);
        if (row < M) v = *(const float4*)(A + (size_t)row*K + k0 + c*8);
        *(float4*)(As + r*80 + c*16) = v;
      }
    }
    #pragma unroll
    for (int i=0;i<2;++i){
      int cid = tid*2+i;
      int r = cid>>2, c = cid&3;
      float4 v = *(const float4*)(Bt + (size_t)(n0+r)*K + k0 + c*8);
      *(float4*)(Bs + r*80 + c*16) = v;
    }
    __syncthreads();
    bf16x8 a[4], b[4];
    #pragma unroll
    for (int i=0;i<4;++i) a[i] = *reinterpret_cast<const bf16x8*>(As + aoff[i]);
    #pragma unroll
    for (int j=0;j<4;++j) b[j] = *reinterpret_cast<const bf16x8*>(Bs + boff[j]);
    #pragma unroll
    for (int i=0;i<4;++i)
      #pragma unroll
      for (int j=0;j<4;++j)
        acc[i][j] = __builtin_amdgcn_mfma_f32_16x16x32_bf16(a[i], b[j], acc[i][j], 0,0,0);
    __syncthreads();
  }

  const int head = (n0>>6) + wc;
  float sv[4][4] = {}, dv[4][4] = {};
  #pragma unroll
  for (int i=0;i<4;++i){
    #pragma unroll
    for (int j=0;j<4;++j){
      int col = n0 + wc*64 + j*16 + l15;
      float asv = a_s[col], adv = a_d[col];
      #pragma unroll
      for (int r=0;r<4;++r){
        int row = m0 + wr*64 + i*16 + l4*4 + r;
        u16 bits = f2b(acc[i][j][r]);
        float valf = b2f((short)bits);
        if (row < M) Cb[(size_t)row*N + col] = bits;
        sv[i][r] = fmaf(valf, asv, sv[i][r]);
        dv[i][r] = fmaf(valf, adv, dv[i][r]);
      }
    }
  }
  #pragma unroll
  for (int i=0;i<4;++i){
    #pragma unroll
    for (int r=0;r<4;++r){
      float s_ = sv[i][r], d_ = dv[i][r];
      #pragma unroll
      for (int mask=1; mask<16; mask<<=1){
        s_ += __shfl_xor(s_, mask);
        d_ += __shfl_xor(d_, mask);
      }
      if (l15==0){
        int row = m0 + wr*64 + i*16 + l4*4 + r;
        if (row < M){ asrc[row*8+head] = s_; adst[row*8+head] = d_; }
      }
    }
  }
}

// ---------------- mega kernel A: count | W1t | W2t | wedot ----------------
__global__ __launch_bounds__(256) void k_prepA(
    const int* __restrict__ dst, const float* __restrict__ ea,
    int* cnt, float* easum, int E, int nbCount,
    const float* __restrict__ W1, u16* __restrict__ W1t,
    const float* __restrict__ W2, u16* __restrict__ W2t,
    const float* __restrict__ We1, const float* __restrict__ ae1,
    const float* __restrict__ We2, const float* __restrict__ ae2,
    float* wedot){
  __shared__ float T[64][65];
  int bx = blockIdx.x;
  int tid = threadIdx.x;
  if (bx < nbCount){
    int e = bx*256 + tid;
    if (e<E){
      int d = dst[e];
      atomicAdd(&cnt[d],1);
      atomicAdd(&easum[d], ea[e]);
    }
    return;
  }
  bx -= nbCount;
  if (bx < 16 + 64){
    const float* W; u16* Wt; int K, t;
    if (bx < 16){ t = bx;      W = W1; Wt = W1t; K = 128; }
    else        { t = bx - 16; W = W2; Wt = W2t; K = 512; }
    const int Nn = 512, nt = 8;
    int k0 = (t/nt)*64, n0 = (t%nt)*64;
    #pragma unroll
    for (int i=0;i<16;++i){
      int id = i*256 + tid;
      int r = id>>6, c = id&63;
      T[r][c] = W[(size_t)(k0+r)*Nn + n0 + c];
    }
    __syncthreads();
    #pragma unroll
    for (int i=0;i<16;++i){
      int id = i*256 + tid;
      int rr = id>>6, cc = id&63;
      Wt[(size_t)(n0+rr)*K + k0 + cc] = f2b(T[cc][rr]);
    }
    return;
  }
  int idx = bx - 80;
  int which = idx>>1, hg = idx&1;
  const float* We = which? We2 : We1;
  const float* ae = which? ae2 : ae1;
  int wv = tid>>6, lane = tid&63;
  int head = hg*4 + wv;
  float p = We[head*64+lane]*ae[head*64+lane];
  #pragma unroll
  for (int o=32;o;o>>=1) p += __shfl_down(p,o);
  if (lane==0) wedot[which*8+head] = p;
}

// ---------------- kernel B: scan | loop-attr ----------------
__global__ __launch_bounds__(256) void k_scanla(
    const int* __restrict__ cnt, int* offs, int N,
    const float* __restrict__ easum, float* la){
  __shared__ int slds[256];
  int bx = blockIdx.x;
  int tid = threadIdx.x;
  if (bx == 0){
    const int chunk = (N + 255)/256;
    const int b = tid*chunk;
    int s = 0;
    for (int i=0;i<chunk;++i){ int idx=b+i; if (idx<N) s += cnt[idx]; }
    slds[tid] = s;
    __syncthreads();
    #pragma unroll
    for (int off=1; off<256; off<<=1){
      int t = (tid>=off)? slds[tid-off] : 0;
      __syncthreads();
      slds[tid] += t;
      __syncthreads();
    }
    int excl = slds[tid] - s;
    for (int i=0;i<chunk;++i){
      int idx=b+i;
      if (idx<N){ offs[idx] = excl; excl += cnt[idx]; }
    }
    if (tid==255) offs[N] = slds[255];
    return;
  }
  int n = (bx-1)*256 + tid;
  if (n<N) la[n] = easum[n] / fmaxf((float)cnt[n], 1.f);
}

// ---------------- kernel C: scatter || GEMM1 (fp32 A) ----------------
__global__ __launch_bounds__(256) void k_scatgemm(
    const int* __restrict__ src, const int* __restrict__ dst,
    const float* __restrict__ ea, const int* __restrict__ offs,
    int* fill, int* srcs, float* eas, int E, int nbScat,
    const float* __restrict__ x, const u16* __restrict__ W1t,
    u16* __restrict__ hb1,
    const float* __restrict__ a_s, const float* __restrict__ a_d,
    float* __restrict__ asrc, float* __restrict__ adst,
    int M, int Nd, int K){
  __shared__ char glds[256*80];
  int bx = blockIdx.x;
  if (bx < nbScat){
    int e = bx*256 + threadIdx.x;
    if (e<E){
      int d = dst[e];
      int p = offs[d] + atomicAdd(&fill[d],1);
      srcs[p] = src[e];
      eas[p]  = ea[e];
    }
    return;
  }
  int t = bx - nbScat;
  gemm_body<1>(x, W1t, hb1, a_s, a_d, asrc, adst, M, Nd, K, t%4, t/4, glds);
}

// standalone GEMM (bf16 A) for layer 2
__global__ __launch_bounds__(256) void k_gemm_mfma(
    const u16* __restrict__ A, const u16* __restrict__ Bt,
    u16* __restrict__ Cb,
    const float* __restrict__ a_s, const float* __restrict__ a_d,
    float* __restrict__ asrc, float* __restrict__ adst,
    int M, int N, int K){
  __shared__ char lds[256*80];
  gemm_body<0>(A, Bt, Cb, a_s, a_d, asrc, adst, M, N, K,
               blockIdx.x, blockIdx.y, lds);
}

// ---------------- single-pass online-softmax aggregate ----------------
// R9 structure: one wave per node; producer lanes (hh=lane&7, esub=lane>>3)
// compute alpha for edges p0+esub / p0+8+esub; consumer lanes (head
// ahh=lane>>3, channels lane*8..+8) pull 16 alphas + src ids via register
// shuffles. NEW vs R9: full 16-edge rounds are BRANCH-FREE -- all 16 bf16x8
// gathers issue back-to-back into registers (16 outstanding loads -> MLP)
// before the exp/FMA chain. Tail round keeps per-edge predication.
// Arithmetic order identical to R9 -> bit-identical result.
__global__ __launch_bounds__(256) void k_flashagg(const u16* __restrict__ hb,
    const int* __restrict__ srcs, const float* __restrict__ eas,
    const int* __restrict__ offs,
    const float* __restrict__ asrc, const float* __restrict__ adst,
    const float* __restrict__ wedot, const float* __restrict__ la,
    const float* __restrict__ bias,
    u16* __restrict__ outb,
    int N, int relu_flag, int self_flag){
  int n = blockIdx.x*4 + (threadIdx.x>>6);
  if (n>=N) return;
  int lane = threadIdx.x&63;
  int hh = lane&7, esub = lane>>3;   // producer role
  int ahh = lane>>3;                 // consumer head
  int c0 = lane*8;                   // consumer channel slot
  int beg = offs[n], end = offs[n+1];
  float wd = wedot[hh];
  float adn = adst[n*8+hh];

  float aselfa = -1e30f;
  if (self_flag){
    float a = asrc[n*8+hh] + adn + la[n]*wd;
    aselfa = a>0.f ? a : 0.2f*a;
  }
  float aself_c = __shfl(aselfa, ahh);

  float m = self_flag ? aself_c : -1e30f;
  float s = 0.f;
  float acc[8] = {};

  int nfull = (end - beg) & ~15;
  int pend_full = beg + nfull;
  int p0 = beg;

  // ---- full rounds: branch-free, 16 gathers in flight ----
  for (; p0 < pend_full; p0 += 16){
    int pA = p0 + esub, pB = pA + 8;
    int sA = srcs[pA], sB = srcs[pB];
    float eaA = eas[pA], eaB = eas[pB];
    float aA = asrc[sA*8+hh] + adn + eaA*wd;  aA = aA>0.f ? aA : 0.2f*aA;
    float aB = asrc[sB*8+hh] + adn + eaB*wd;  aB = aB>0.f ? aB : 0.2f*aB;
    float av[16]; int se[16];
    #pragma unroll
    for (int e=0;e<8;++e){ av[e]   = __shfl(aA, e*8 + ahh); se[e]   = __shfl(sA, e*8); }
    #pragma unroll
    for (int e=0;e<8;++e){ av[8+e] = __shfl(aB, e*8 + ahh); se[8+e] = __shfl(sB, e*8); }
    float mo = m;
    #pragma unroll
    for (int e=0;e<16;++e) mo = fmaxf(mo, av[e]);
    float f = __expf(m - mo);
    m = mo;
    s *= f;
    #pragma unroll
    for (int j=0;j<8;++j) acc[j] *= f;
    // issue all 16 row-gathers unconditionally
    bf16x8 v[16];
    #pragma unroll
    for (int e=0;e<16;++e) v[e] = *(const bf16x8*)(hb + (size_t)se[e]*512 + c0);
    #pragma unroll
    for (int e=0;e<16;++e){
      float ee = __expf(av[e] - m);
      s += ee;
      #pragma unroll
      for (int j=0;j<8;++j) acc[j] = fmaf(ee, b2f(v[e][j]), acc[j]);
    }
  }

  // ---- tail round (<16 edges): predicated, same as R9 ----
  if (p0 < end){
    int pA = p0 + esub, pB = p0 + 8 + esub;
    float aA = -1e30f, aB = -1e30f;
    int sA = 0, sB = 0;
    if (pA < end){
      sA = srcs[pA];
      float a0 = asrc[sA*8+hh] + adn + eas[pA]*wd;
      aA = a0>0.f ? a0 : 0.2f*a0;
    }
    if (pB < end){
      sB = srcs[pB];
      float a0 = asrc[sB*8+hh] + adn + eas[pB]*wd;
      aB = a0>0.f ? a0 : 0.2f*a0;
    }
    float av[16]; int se[16];
    #pragma unroll
    for (int e=0;e<8;++e){ av[e]   = __shfl(aA, e*8 + ahh); se[e]   = __shfl(sA, e*8); }
    #pragma unroll
    for (int e=0;e<8;++e){ av[8+e] = __shfl(aB, e*8 + ahh); se[8+e] = __shfl(sB, e*8); }
    float mo = m;
    #pragma unroll
    for (int e=0;e<16;++e) mo = fmaxf(mo, av[e]);
    float f = __expf(m - mo);
    m = mo;
    s *= f;
    #pragma unroll
    for (int j=0;j<8;++j) acc[j] *= f;
    #pragma unroll
    for (int e=0;e<16;++e){
      if (p0 + e < end){
        float ee = __expf(av[e] - m);
        s += ee;
        bf16x8 v0 = *(const bf16x8*)(hb + (size_t)se[e]*512 + c0);
        #pragma unroll
        for (int j=0;j<8;++j) acc[j] = fmaf(ee, b2f(v0[j]), acc[j]);
      }
    }
  }

  if (self_flag){
    float xs = __expf(aself_c - m);
    s += xs;
    bf16x8 v0 = *(const bf16x8*)(hb + (size_t)n*512 + c0);
    #pragma unroll
    for (int j=0;j<8;++j) acc[j] = fmaf(xs, b2f(v0[j]), acc[j]);
  }
  float iv = 1.f/(s + 1e-16f);
  bf16x8 ov;
  #pragma unroll
  for (int j=0;j<8;++j){
    float val = acc[j]*iv + bias[c0+j];
    if (relu_flag) val = fmaxf(val, 0.f);
    ov[j] = (short)f2b(val);
  }
  *(bf16x8*)(outb + (size_t)n*512 + c0) = ov;
}

// column mean over bf16 rows: 512 threads (one per channel), 16 rows/block
__global__ __launch_bounds__(512) void k_colmean(const u16* __restrict__ out2b,
                          float* __restrict__ o, int N, float invN){
  int c = threadIdx.x;
  int n0 = blockIdx.x*16;
  int nend = min(n0+16, N);
  float s = 0.f;
  for (int n=n0;n<nend;++n) s += b2f(out2b[(size_t)n*512 + c]);
  atomicAdd(&o[c], s*invN);
}

extern "C" void kernel_launch(void* const* d_in, const int* in_sizes, int n_in,
                              void* d_out, int out_size, void* d_ws, size_t ws_size,
                              hipStream_t stream){
  const float* x   = (const float*)d_in[0];
  const int* eidx  = (const int*)d_in[1];
  const float* ea  = (const float*)d_in[2];
  const float* W1  = (const float*)d_in[3];
  const float* We1 = (const float*)d_in[4];
  const float* as1 = (const float*)d_in[5];
  const float* ad1 = (const float*)d_in[6];
  const float* ae1 = (const float*)d_in[7];
  const float* b1  = (const float*)d_in[8];
  const float* W2  = (const float*)d_in[9];
  const float* We2 = (const float*)d_in[10];
  const float* as2 = (const float*)d_in[11];
  const float* ad2 = (const float*)d_in[12];
  const float* ae2 = (const float*)d_in[13];
  const float* b2  = (const float*)d_in[14];
  float* outp = (float*)d_out;

  const int FIN = 128, D1 = 512;
  const int N = in_sizes[0]/FIN;
  const int E = in_sizes[1]/2;
  const int* srcA = eidx;
  const int* dstA = eidx + E;

  char* ws = (char*)d_ws;
  size_t o = 0;
  auto alloc = [&](size_t bytes)->void*{
    void* p = ws + o; o = (o + bytes + 255) & ~(size_t)255; return p;
  };
  u16*   hb1   = (u16*)  alloc((size_t)N*D1*2);   // layer1 features, bf16
  u16*   hb2   = (u16*)  alloc((size_t)N*D1*2);   // layer2 features, bf16
  u16*   out1rb= (u16*)  alloc((size_t)N*D1*2);   // relu(layer1 out), bf16
  u16*   out2b = (u16*)  alloc((size_t)N*D1*2);   // layer2 out, bf16
  u16*   W1t   = (u16*)  alloc((size_t)D1*FIN*2); // [512][128]
  u16*   W2t   = (u16*)  alloc((size_t)D1*D1*2);  // [512][512]
  int*   srcs  = (int*)  alloc((size_t)E*4);
  float* eas   = (float*)alloc((size_t)E*4);
  int*   offs  = (int*)  alloc((size_t)(N+1)*4);
  size_t zbeg = o;
  int*   cnt   = (int*)  alloc((size_t)N*4);
  int*   fill  = (int*)  alloc((size_t)N*4);
  float* easum = (float*)alloc((size_t)N*4);
  size_t zend = o;
  float* asrc  = (float*)alloc((size_t)N*8*4);
  float* adst  = (float*)alloc((size_t)N*8*4);
  float* la    = (float*)alloc((size_t)N*4);
  float* wedot = (float*)alloc(64);
  (void)ws_size; (void)n_in;

  hipMemsetAsync(ws + zbeg, 0, zend - zbeg, stream);
  hipMemsetAsync(d_out, 0, (size_t)out_size*sizeof(float), stream);

  dim3 b256(256);
  int ge = (E+255)/256;          // 625
  int gn4 = (N+3)/4;             // flashagg: 4 nodes/block (1 wave each)

  // A: count | W1 transpose | W2 transpose | wedot
  k_prepA<<<ge + 16 + 64 + 4, b256, 0, stream>>>(
      dstA, ea, cnt, easum, E, ge,
      W1, W1t, W2, W2t, We1, ae1, We2, ae2, wedot);

  // B: scan | loop-attr
  k_scanla<<<1 + (N+255)/256, b256, 0, stream>>>(cnt, offs, N, easum, la);

  // C: scatter || GEMM1 (fp32 A, in-register bf16 round)
  int nbG1 = (D1/128)*((N+127)/128);
  k_scatgemm<<<ge + nbG1, b256, 0, stream>>>(
      srcA, dstA, ea, offs, fill, srcs, eas, E, ge,
      x, W1t, hb1, as1, ad1, asrc, adst, N, D1, FIN);

  // D: layer-1 flash aggregate
  k_flashagg<<<gn4, b256, 0, stream>>>(hb1, srcs, eas, offs, asrc, adst,
                                       wedot, la, b1, out1rb, N, 1, 0);

  // E: GEMM2 (bf16 A) + alpha epilogue
  k_gemm_mfma<<<dim3(D1/128, (N+127)/128), b256, 0, stream>>>(
      out1rb, W2t, hb2, as2, ad2, asrc, adst, N, D1, D1);

  // F: layer-2 flash aggregate (self loops, fill='mean')
  k_flashagg<<<gn4, b256, 0, stream>>>(hb2, srcs, eas, offs, asrc, adst,
                                       wedot+8, la, b2, out2b, N, 0, 1);

  // G: mean over nodes
  k_colmean<<<(N+15)/16, 512, 0, stream>>>(out2b, outp, N, 1.0f/(float)N);
}

// Round 13
// 175.142 us; speedup vs baseline: 1.4873x; 1.0495x over previous
//
#include <hip/hip_runtime.h>
#include <hip/hip_bf16.h>

#define HD __device__ __forceinline__
typedef unsigned short u16;
typedef __attribute__((ext_vector_type(8))) short bf16x8;
typedef __attribute__((ext_vector_type(4))) float f32x4;

// round-to-nearest-even fp32 -> bf16 bits
HD u16 f2b(float f){
  unsigned u = __float_as_uint(f);
  unsigned r = (u + 0x7fffu + ((u>>16)&1u)) >> 16;
  return (u16)r;
}
HD float b2f(short s){ return __uint_as_float(((unsigned)(u16)s)<<16); }

// ---------------- shared GEMM body ----------------
// Cb[M,N] = A[M,K] @ Bt[N,K]^T (bf16 out) + fused alpha epilogue (see R8).
// tile 128x128, BK=32, 256 thr = 4 waves 2x2. AF32: fp32 A, bf16-rounded
// in-register during staging (bit-identical to a separate cast pass).
template<int AF32>
HD void gemm_body(const void* Ap, const u16* __restrict__ Bt,
                  u16* __restrict__ Cb,
                  const float* __restrict__ a_s, const float* __restrict__ a_d,
                  float* __restrict__ asrc, float* __restrict__ adst,
                  int M, int N, int K, int bidx, int bidy, char* lds){
  char* As = lds;
  char* Bs = lds + 128*80;   // row stride 80B - conflict-free
  const int tid = threadIdx.x;
  const int lane = tid & 63, w = tid >> 6;
  const int wr = w >> 1, wc = w & 1;
  const int l15 = lane & 15, l4 = lane >> 4;
  const int m0 = bidy*128, n0 = bidx*128;

  f32x4 acc[4][4] = {};
  int aoff[4], boff[4];
  #pragma unroll
  for (int i=0;i<4;++i) aoff[i] = (wr*64 + i*16 + l15)*80 + l4*16;
  #pragma unroll
  for (int j=0;j<4;++j) boff[j] = (wc*64 + j*16 + l15)*80 + l4*16;

  for (int k0=0; k0<K; k0+=32){
    #pragma unroll
    for (int i=0;i<2;++i){
      int cid = tid*2+i;
      int r = cid>>2, c = cid&3;
      int row = m0 + r;
      if (AF32){
        const float* A = (const float*)Ap;
        float4 v0 = make_float4(0.f,0.f,0.f,0.f), v1 = v0;
        if (row < M){
          v0 = *(const float4*)(A + (size_t)row*K + k0 + c*8);
          v1 = *(const float4*)(A + (size_t)row*K + k0 + c*8 + 4);
        }
        ushort4 o0, o1;
        o0.x=f2b(v0.x); o0.y=f2b(v0.y); o0.z=f2b(v0.z); o0.w=f2b(v0.w);
        o1.x=f2b(v1.x); o1.y=f2b(v1.y); o1.z=f2b(v1.z); o1.w=f2b(v1.w);
        *(ushort4*)(As + r*80 + c*16)     = o0;
        *(ushort4*)(As + r*80 + c*16 + 8) = o1;
      } else {
        const u16* A = (const u16*)Ap;
        float4 v = make_float4(0.f,0.f,0.f,0.f);
        if (row < M) v = *(const float4*)(A + (size_t)row*K + k0 + c*8);
        *(float4*)(As + r*80 + c*16) = v;
      }
    }
    #pragma unroll
    for (int i=0;i<2;++i){
      int cid = tid*2+i;
      int r = cid>>2, c = cid&3;
      float4 v = *(const float4*)(Bt + (size_t)(n0+r)*K + k0 + c*8);
      *(float4*)(Bs + r*80 + c*16) = v;
    }
    __syncthreads();
    bf16x8 a[4], b[4];
    #pragma unroll
    for (int i=0;i<4;++i) a[i] = *reinterpret_cast<const bf16x8*>(As + aoff[i]);
    #pragma unroll
    for (int j=0;j<4;++j) b[j] = *reinterpret_cast<const bf16x8*>(Bs + boff[j]);
    #pragma unroll
    for (int i=0;i<4;++i)
      #pragma unroll
      for (int j=0;j<4;++j)
        acc[i][j] = __builtin_amdgcn_mfma_f32_16x16x32_bf16(a[i], b[j], acc[i][j], 0,0,0);
    __syncthreads();
  }

  const int head = (n0>>6) + wc;
  float sv[4][4] = {}, dv[4][4] = {};
  #pragma unroll
  for (int i=0;i<4;++i){
    #pragma unroll
    for (int j=0;j<4;++j){
      int col = n0 + wc*64 + j*16 + l15;
      float asv = a_s[col], adv = a_d[col];
      #pragma unroll
      for (int r=0;r<4;++r){
        int row = m0 + wr*64 + i*16 + l4*4 + r;
        u16 bits = f2b(acc[i][j][r]);
        float valf = b2f((short)bits);
        if (row < M) Cb[(size_t)row*N + col] = bits;
        sv[i][r] = fmaf(valf, asv, sv[i][r]);
        dv[i][r] = fmaf(valf, adv, dv[i][r]);
      }
    }
  }
  #pragma unroll
  for (int i=0;i<4;++i){
    #pragma unroll
    for (int r=0;r<4;++r){
      float s_ = sv[i][r], d_ = dv[i][r];
      #pragma unroll
      for (int mask=1; mask<16; mask<<=1){
        s_ += __shfl_xor(s_, mask);
        d_ += __shfl_xor(d_, mask);
      }
      if (l15==0){
        int row = m0 + wr*64 + i*16 + l4*4 + r;
        if (row < M){ asrc[row*8+head] = s_; adst[row*8+head] = d_; }
      }
    }
  }
}

// ---------------- mega kernel A: count | W1t | W2t | wedot ----------------
__global__ __launch_bounds__(256) void k_prepA(
    const int* __restrict__ dst, const float* __restrict__ ea,
    int* cnt, float* easum, int E, int nbCount,
    const float* __restrict__ W1, u16* __restrict__ W1t,
    const float* __restrict__ W2, u16* __restrict__ W2t,
    const float* __restrict__ We1, const float* __restrict__ ae1,
    const float* __restrict__ We2, const float* __restrict__ ae2,
    float* wedot){
  __shared__ float T[64][65];
  int bx = blockIdx.x;
  int tid = threadIdx.x;
  if (bx < nbCount){
    int e = bx*256 + tid;
    if (e<E){
      int d = dst[e];
      atomicAdd(&cnt[d],1);
      atomicAdd(&easum[d], ea[e]);
    }
    return;
  }
  bx -= nbCount;
  if (bx < 16 + 64){
    const float* W; u16* Wt; int K, t;
    if (bx < 16){ t = bx;      W = W1; Wt = W1t; K = 128; }
    else        { t = bx - 16; W = W2; Wt = W2t; K = 512; }
    const int Nn = 512, nt = 8;
    int k0 = (t/nt)*64, n0 = (t%nt)*64;
    #pragma unroll
    for (int i=0;i<16;++i){
      int id = i*256 + tid;
      int r = id>>6, c = id&63;
      T[r][c] = W[(size_t)(k0+r)*Nn + n0 + c];
    }
    __syncthreads();
    #pragma unroll
    for (int i=0;i<16;++i){
      int id = i*256 + tid;
      int rr = id>>6, cc = id&63;
      Wt[(size_t)(n0+rr)*K + k0 + cc] = f2b(T[cc][rr]);
    }
    return;
  }
  int idx = bx - 80;
  int which = idx>>1, hg = idx&1;
  const float* We = which? We2 : We1;
  const float* ae = which? ae2 : ae1;
  int wv = tid>>6, lane = tid&63;
  int head = hg*4 + wv;
  float p = We[head*64+lane]*ae[head*64+lane];
  #pragma unroll
  for (int o=32;o;o>>=1) p += __shfl_down(p,o);
  if (lane==0) wedot[which*8+head] = p;
}

// ---------------- kernel B: scan | loop-attr ----------------
__global__ __launch_bounds__(256) void k_scanla(
    const int* __restrict__ cnt, int* offs, int N,
    const float* __restrict__ easum, float* la){
  __shared__ int slds[256];
  int bx = blockIdx.x;
  int tid = threadIdx.x;
  if (bx == 0){
    const int chunk = (N + 255)/256;
    const int b = tid*chunk;
    int s = 0;
    for (int i=0;i<chunk;++i){ int idx=b+i; if (idx<N) s += cnt[idx]; }
    slds[tid] = s;
    __syncthreads();
    #pragma unroll
    for (int off=1; off<256; off<<=1){
      int t = (tid>=off)? slds[tid-off] : 0;
      __syncthreads();
      slds[tid] += t;
      __syncthreads();
    }
    int excl = slds[tid] - s;
    for (int i=0;i<chunk;++i){
      int idx=b+i;
      if (idx<N){ offs[idx] = excl; excl += cnt[idx]; }
    }
    if (tid==255) offs[N] = slds[255];
    return;
  }
  int n = (bx-1)*256 + tid;
  if (n<N) la[n] = easum[n] / fmaxf((float)cnt[n], 1.f);
}

// ---------------- kernel C: scatter || GEMM1 (fp32 A) ----------------
__global__ __launch_bounds__(256) void k_scatgemm(
    const int* __restrict__ src, const int* __restrict__ dst,
    const float* __restrict__ ea, const int* __restrict__ offs,
    int* fill, int* srcs, float* eas, int E, int nbScat,
    const float* __restrict__ x, const u16* __restrict__ W1t,
    u16* __restrict__ hb1,
    const float* __restrict__ a_s, const float* __restrict__ a_d,
    float* __restrict__ asrc, float* __restrict__ adst,
    int M, int Nd, int K){
  __shared__ char glds[256*80];
  int bx = blockIdx.x;
  if (bx < nbScat){
    int e = bx*256 + threadIdx.x;
    if (e<E){
      int d = dst[e];
      int p = offs[d] + atomicAdd(&fill[d],1);
      srcs[p] = src[e];
      eas[p]  = ea[e];
    }
    return;
  }
  int t = bx - nbScat;
  gemm_body<1>(x, W1t, hb1, a_s, a_d, asrc, adst, M, Nd, K, t%4, t/4, glds);
}

// standalone GEMM (bf16 A) for layer 2
__global__ __launch_bounds__(256) void k_gemm_mfma(
    const u16* __restrict__ A, const u16* __restrict__ Bt,
    u16* __restrict__ Cb,
    const float* __restrict__ a_s, const float* __restrict__ a_d,
    float* __restrict__ asrc, float* __restrict__ adst,
    int M, int N, int K){
  __shared__ char lds[256*80];
  gemm_body<0>(A, Bt, Cb, a_s, a_d, asrc, adst, M, N, K,
               blockIdx.x, blockIdx.y, lds);
}

// ---------------- single-pass online-softmax aggregate ----------------
// R9 structure: one wave per node; producer lanes (hh=lane&7, esub=lane>>3)
// compute alpha for edges p0+esub / p0+8+esub; consumer lanes (head
// ahh=lane>>3, channels lane*8..+8) pull 16 alphas + src ids via register
// shuffles. Full 16-edge rounds use a DEPTH-4 ROTATED gather pipeline:
// only 4 bf16x8 gather registers live (vs R12's 16 -> occupancy loss),
// each consume overlaps the load 4 edges ahead. Arithmetic order identical
// to R9 -> bit-identical result (absmax must stay 0.001953125).
__global__ __launch_bounds__(256) void k_flashagg(const u16* __restrict__ hb,
    const int* __restrict__ srcs, const float* __restrict__ eas,
    const int* __restrict__ offs,
    const float* __restrict__ asrc, const float* __restrict__ adst,
    const float* __restrict__ wedot, const float* __restrict__ la,
    const float* __restrict__ bias,
    u16* __restrict__ outb,
    int N, int relu_flag, int self_flag){
  int n = blockIdx.x*4 + (threadIdx.x>>6);
  if (n>=N) return;
  int lane = threadIdx.x&63;
  int hh = lane&7, esub = lane>>3;   // producer role
  int ahh = lane>>3;                 // consumer head
  int c0 = lane*8;                   // consumer channel slot
  int beg = offs[n], end = offs[n+1];
  float wd = wedot[hh];
  float adn = adst[n*8+hh];

  float aselfa = -1e30f;
  if (self_flag){
    float a = asrc[n*8+hh] + adn + la[n]*wd;
    aselfa = a>0.f ? a : 0.2f*a;
  }
  float aself_c = __shfl(aselfa, ahh);

  float m = self_flag ? aself_c : -1e30f;
  float s = 0.f;
  float acc[8] = {};

  int nfull = (end - beg) & ~15;
  int pend_full = beg + nfull;
  int p0 = beg;

  // ---- full rounds: depth-4 rotated gather pipeline ----
  for (; p0 < pend_full; p0 += 16){
    int pA = p0 + esub, pB = pA + 8;
    int sA = srcs[pA], sB = srcs[pB];
    float eaA = eas[pA], eaB = eas[pB];
    float aA = asrc[sA*8+hh] + adn + eaA*wd;  aA = aA>0.f ? aA : 0.2f*aA;
    float aB = asrc[sB*8+hh] + adn + eaB*wd;  aB = aB>0.f ? aB : 0.2f*aB;
    float av[16]; int se[16];
    #pragma unroll
    for (int e=0;e<8;++e){ av[e]   = __shfl(aA, e*8 + ahh); se[e]   = __shfl(sA, e*8); }
    #pragma unroll
    for (int e=0;e<8;++e){ av[8+e] = __shfl(aB, e*8 + ahh); se[8+e] = __shfl(sB, e*8); }
    float mo = m;
    #pragma unroll
    for (int e=0;e<16;++e) mo = fmaxf(mo, av[e]);
    float f = __expf(m - mo);
    m = mo;
    s *= f;
    #pragma unroll
    for (int j=0;j<8;++j) acc[j] *= f;

    #define GATHER_(e) (*(const bf16x8*)(hb + (size_t)se[e]*512 + c0))
    #define CONS_(e, vv) do{ float ee_ = __expf(av[e] - m); s += ee_; \
      _Pragma("unroll") \
      for (int j=0;j<8;++j) acc[j] = fmaf(ee_, b2f((vv)[j]), acc[j]); }while(0)

    bf16x8 va = GATHER_(0), vb = GATHER_(1), vc = GATHER_(2), vd = GATHER_(3);
    CONS_(0,  va); va = GATHER_(4);
    CONS_(1,  vb); vb = GATHER_(5);
    CONS_(2,  vc); vc = GATHER_(6);
    CONS_(3,  vd); vd = GATHER_(7);
    CONS_(4,  va); va = GATHER_(8);
    CONS_(5,  vb); vb = GATHER_(9);
    CONS_(6,  vc); vc = GATHER_(10);
    CONS_(7,  vd); vd = GATHER_(11);
    CONS_(8,  va); va = GATHER_(12);
    CONS_(9,  vb); vb = GATHER_(13);
    CONS_(10, vc); vc = GATHER_(14);
    CONS_(11, vd); vd = GATHER_(15);
    CONS_(12, va);
    CONS_(13, vb);
    CONS_(14, vc);
    CONS_(15, vd);
    #undef GATHER_
    #undef CONS_
  }

  // ---- tail round (<16 edges): predicated, same as R9 ----
  if (p0 < end){
    int pA = p0 + esub, pB = p0 + 8 + esub;
    float aA = -1e30f, aB = -1e30f;
    int sA = 0, sB = 0;
    if (pA < end){
      sA = srcs[pA];
      float a0 = asrc[sA*8+hh] + adn + eas[pA]*wd;
      aA = a0>0.f ? a0 : 0.2f*a0;
    }
    if (pB < end){
      sB = srcs[pB];
      float a0 = asrc[sB*8+hh] + adn + eas[pB]*wd;
      aB = a0>0.f ? a0 : 0.2f*a0;
    }
    float av[16]; int se[16];
    #pragma unroll
    for (int e=0;e<8;++e){ av[e]   = __shfl(aA, e*8 + ahh); se[e]   = __shfl(sA, e*8); }
    #pragma unroll
    for (int e=0;e<8;++e){ av[8+e] = __shfl(aB, e*8 + ahh); se[8+e] = __shfl(sB, e*8); }
    float mo = m;
    #pragma unroll
    for (int e=0;e<16;++e) mo = fmaxf(mo, av[e]);
    float f = __expf(m - mo);
    m = mo;
    s *= f;
    #pragma unroll
    for (int j=0;j<8;++j) acc[j] *= f;
    #pragma unroll
    for (int e=0;e<16;++e){
      if (p0 + e < end){
        float ee = __expf(av[e] - m);
        s += ee;
        bf16x8 v0 = *(const bf16x8*)(hb + (size_t)se[e]*512 + c0);
        #pragma unroll
        for (int j=0;j<8;++j) acc[j] = fmaf(ee, b2f(v0[j]), acc[j]);
      }
    }
  }

  if (self_flag){
    float xs = __expf(aself_c - m);
    s += xs;
    bf16x8 v0 = *(const bf16x8*)(hb + (size_t)n*512 + c0);
    #pragma unroll
    for (int j=0;j<8;++j) acc[j] = fmaf(xs, b2f(v0[j]), acc[j]);
  }
  float iv = 1.f/(s + 1e-16f);
  bf16x8 ov;
  #pragma unroll
  for (int j=0;j<8;++j){
    float val = acc[j]*iv + bias[c0+j];
    if (relu_flag) val = fmaxf(val, 0.f);
    ov[j] = (short)f2b(val);
  }
  *(bf16x8*)(outb + (size_t)n*512 + c0) = ov;
}

// column mean over bf16 rows: 512 threads (one per channel), 16 rows/block
__global__ __launch_bounds__(512) void k_colmean(const u16* __restrict__ out2b,
                          float* __restrict__ o, int N, float invN){
  int c = threadIdx.x;
  int n0 = blockIdx.x*16;
  int nend = min(n0+16, N);
  float s = 0.f;
  for (int n=n0;n<nend;++n) s += b2f(out2b[(size_t)n*512 + c]);
  atomicAdd(&o[c], s*invN);
}

extern "C" void kernel_launch(void* const* d_in, const int* in_sizes, int n_in,
                              void* d_out, int out_size, void* d_ws, size_t ws_size,
                              hipStream_t stream){
  const float* x   = (const float*)d_in[0];
  const int* eidx  = (const int*)d_in[1];
  const float* ea  = (const float*)d_in[2];
  const float* W1  = (const float*)d_in[3];
  const float* We1 = (const float*)d_in[4];
  const float* as1 = (const float*)d_in[5];
  const float* ad1 = (const float*)d_in[6];
  const float* ae1 = (const float*)d_in[7];
  const float* b1  = (const float*)d_in[8];
  const float* W2  = (const float*)d_in[9];
  const float* We2 = (const float*)d_in[10];
  const float* as2 = (const float*)d_in[11];
  const float* ad2 = (const float*)d_in[12];
  const float* ae2 = (const float*)d_in[13];
  const float* b2  = (const float*)d_in[14];
  float* outp = (float*)d_out;

  const int FIN = 128, D1 = 512;
  const int N = in_sizes[0]/FIN;
  const int E = in_sizes[1]/2;
  const int* srcA = eidx;
  const int* dstA = eidx + E;

  char* ws = (char*)d_ws;
  size_t o = 0;
  auto alloc = [&](size_t bytes)->void*{
    void* p = ws + o; o = (o + bytes + 255) & ~(size_t)255; return p;
  };
  u16*   hb1   = (u16*)  alloc((size_t)N*D1*2);   // layer1 features, bf16
  u16*   hb2   = (u16*)  alloc((size_t)N*D1*2);   // layer2 features, bf16
  u16*   out1rb= (u16*)  alloc((size_t)N*D1*2);   // relu(layer1 out), bf16
  u16*   out2b = (u16*)  alloc((size_t)N*D1*2);   // layer2 out, bf16
  u16*   W1t   = (u16*)  alloc((size_t)D1*FIN*2); // [512][128]
  u16*   W2t   = (u16*)  alloc((size_t)D1*D1*2);  // [512][512]
  int*   srcs  = (int*)  alloc((size_t)E*4);
  float* eas   = (float*)alloc((size_t)E*4);
  int*   offs  = (int*)  alloc((size_t)(N+1)*4);
  size_t zbeg = o;
  int*   cnt   = (int*)  alloc((size_t)N*4);
  int*   fill  = (int*)  alloc((size_t)N*4);
  float* easum = (float*)alloc((size_t)N*4);
  size_t zend = o;
  float* asrc  = (float*)alloc((size_t)N*8*4);
  float* adst  = (float*)alloc((size_t)N*8*4);
  float* la    = (float*)alloc((size_t)N*4);
  float* wedot = (float*)alloc(64);
  (void)ws_size; (void)n_in;

  hipMemsetAsync(ws + zbeg, 0, zend - zbeg, stream);
  hipMemsetAsync(d_out, 0, (size_t)out_size*sizeof(float), stream);

  dim3 b256(256);
  int ge = (E+255)/256;          // 625
  int gn4 = (N+3)/4;             // flashagg: 4 nodes/block (1 wave each)

  // A: count | W1 transpose | W2 transpose | wedot
  k_prepA<<<ge + 16 + 64 + 4, b256, 0, stream>>>(
      dstA, ea, cnt, easum, E, ge,
      W1, W1t, W2, W2t, We1, ae1, We2, ae2, wedot);

  // B: scan | loop-attr
  k_scanla<<<1 + (N+255)/256, b256, 0, stream>>>(cnt, offs, N, easum, la);

  // C: scatter || GEMM1 (fp32 A, in-register bf16 round)
  int nbG1 = (D1/128)*((N+127)/128);
  k_scatgemm<<<ge + nbG1, b256, 0, stream>>>(
      srcA, dstA, ea, offs, fill, srcs, eas, E, ge,
      x, W1t, hb1, as1, ad1, asrc, adst, N, D1, FIN);

  // D: layer-1 flash aggregate
  k_flashagg<<<gn4, b256, 0, stream>>>(hb1, srcs, eas, offs, asrc, adst,
                                       wedot, la, b1, out1rb, N, 1, 0);

  // E: GEMM2 (bf16 A) + alpha epilogue
  k_gemm_mfma<<<dim3(D1/128, (N+127)/128), b256, 0, stream>>>(
      out1rb, W2t, hb2, as2, ad2, asrc, adst, N, D1, D1);

  // F: layer-2 flash aggregate (self loops, fill='mean')
  k_flashagg<<<gn4, b256, 0, stream>>>(hb2, srcs, eas, offs, asrc, adst,
                                       wedot+8, la, b2, out2b, N, 0, 1);

  // G: mean over nodes
  k_colmean<<<(N+15)/16, 512, 0, stream>>>(out2b, outp, N, 1.0f/(float)N);
}